// Round 1
// baseline (1187.088 us; speedup 1.0000x reference)
//
#include <hip/hip_runtime.h>
#include <math.h>

#define NN 50000
#define NE 800000
#define IND 256
#define ED 64
#define EMB 128
#define NH 8
#define HD 16

__device__ __forceinline__ float mishf(float v) {
    // mish(v) = v * tanh(softplus(v)) = v * ((1+e^v)^2 - 1) / ((1+e^v)^2 + 1)
    float t = expf(fminf(v, 20.f));   // clamp: for v>20 ratio==1 in fp32 anyway
    float u = 1.f + t;
    u = u * u;
    return v * ((u - 1.f) / (u + 1.f));
}

// ---------------- node projection: h = X @ W + b  [50000,256]@[256,128] ----
__global__ __launch_bounds__(256) void k_node_proj(
    const float* __restrict__ X, const float* __restrict__ W,
    const float* __restrict__ b, float* __restrict__ hout) {
    __shared__ float As[32][32];
    __shared__ float Ws[32][128];
    const int row0 = blockIdx.x * 32;
    const int tid = threadIdx.x;
    const int col = (tid & 31) * 4;   // 4 consecutive cols
    const int rb  = (tid >> 5) * 4;   // 4 consecutive rows
    float acc[4][4] = {};
    for (int k0 = 0; k0 < IND; k0 += 32) {
        {   // stage A tile 32x32
            int r = tid >> 5, kk = tid & 31;
            #pragma unroll
            for (int i = 0; i < 4; ++i) {
                int rr = r + i * 8;
                int gr = row0 + rr;
                As[rr][kk] = (gr < NN) ? X[(size_t)gr * IND + k0 + kk] : 0.f;
            }
        }
        {   // stage W tile 32x128
            int j = tid & 127, kb = tid >> 7;
            #pragma unroll
            for (int i = 0; i < 16; ++i) {
                int kk = kb + i * 2;
                Ws[kk][j] = W[(size_t)(k0 + kk) * EMB + j];
            }
        }
        __syncthreads();
        #pragma unroll
        for (int kk = 0; kk < 32; ++kk) {
            float4 wv = *(const float4*)&Ws[kk][col];
            float av[4];
            #pragma unroll
            for (int r = 0; r < 4; ++r) av[r] = As[rb + r][kk];
            #pragma unroll
            for (int r = 0; r < 4; ++r) {
                acc[r][0] = fmaf(av[r], wv.x, acc[r][0]);
                acc[r][1] = fmaf(av[r], wv.y, acc[r][1]);
                acc[r][2] = fmaf(av[r], wv.z, acc[r][2]);
                acc[r][3] = fmaf(av[r], wv.w, acc[r][3]);
            }
        }
        __syncthreads();
    }
    #pragma unroll
    for (int r = 0; r < 4; ++r) {
        int gr = row0 + rb + r;
        if (gr < NN) {
            float4 o;
            o.x = acc[r][0] + b[col];
            o.y = acc[r][1] + b[col + 1];
            o.z = acc[r][2] + b[col + 2];
            o.w = acc[r][3] + b[col + 3];
            *(float4*)&hout[(size_t)gr * EMB + col] = o;
        }
    }
}

// ---------- fused edge pass A: proj + gather + mish + logits + exp + denom --
// 1 wave handles 8 edges; lane l owns output cols l and l+64.
__global__ __launch_bounds__(256) void k_edge_attn(
    const float* __restrict__ EF, const float* __restrict__ We,
    const float* __restrict__ Web, const float* __restrict__ Av,
    const float* __restrict__ hbuf, const int* __restrict__ snd,
    const int* __restrict__ rcv, float* __restrict__ exbuf,
    float* __restrict__ denom) {
    __shared__ float Ws[ED * EMB];   // 32 KB
    for (int i = threadIdx.x; i < ED * EMB; i += 256) Ws[i] = We[i];
    __syncthreads();
    const int l = threadIdx.x & 63;
    const int wid = (blockIdx.x << 2) + (threadIdx.x >> 6);
    const int nW = gridDim.x << 2;
    const float b0 = Web[l], b1 = Web[l + 64];
    const float a0 = Av[l], a1 = Av[l + 64];
    const int h0 = l >> 4, h1 = 4 + (l >> 4);
    for (int g = wid; g < NE / 8; g += nW) {
        const int e0 = g * 8;
        float ef[8];
        #pragma unroll
        for (int i = 0; i < 8; ++i) ef[i] = EF[(size_t)(e0 + i) * ED + l];
        float acc0[8], acc1[8];
        #pragma unroll
        for (int i = 0; i < 8; ++i) { acc0[i] = b0; acc1[i] = b1; }
        #pragma unroll
        for (int kk = 0; kk < ED; ++kk) {
            float w0 = Ws[kk * EMB + l];
            float w1 = Ws[kk * EMB + l + 64];
            #pragma unroll
            for (int i = 0; i < 8; ++i) {
                float efk = __int_as_float(
                    __builtin_amdgcn_readlane(__float_as_int(ef[i]), kk));
                acc0[i] = fmaf(efk, w0, acc0[i]);
                acc1[i] = fmaf(efk, w1, acc1[i]);
            }
        }
        #pragma unroll
        for (int i = 0; i < 8; ++i) {
            const int e = e0 + i;
            const int s = snd[e], r = rcv[e];
            float hs0 = hbuf[(size_t)s * EMB + l];
            float hs1 = hbuf[(size_t)s * EMB + l + 64];
            float hr0 = hbuf[(size_t)r * EMB + l];
            float hr1 = hbuf[(size_t)r * EMB + l + 64];
            float m0 = mishf(hs0 + hr0 + acc0[i]);
            float m1 = mishf(hs1 + hr1 + acc1[i]);
            float p0 = m0 * a0, p1 = m1 * a1;
            #pragma unroll
            for (int off = 8; off >= 1; off >>= 1) {
                p0 += __shfl_xor(p0, off, 64);
                p1 += __shfl_xor(p1, off, 64);
            }
            // no max-subtraction: logits are O(10), exp safe in fp32,
            // weights = ex/sum(ex) identical to reference's shifted form
            float ex0 = expf(p0), ex1 = expf(p1);
            if ((l & 15) == 0) {
                exbuf[(size_t)e * NH + h0] = ex0;
                exbuf[(size_t)e * NH + h1] = ex1;
                atomicAdd(&denom[(size_t)r * NH + h0], ex0);
                atomicAdd(&denom[(size_t)r * NH + h1], ex1);
            }
        }
    }
}

// --------- pass C: weights = ex/denom[r]; out[r] += w * h[s] (atomics) -----
__global__ __launch_bounds__(256) void k_scatter(
    const float* __restrict__ hbuf, const int* __restrict__ snd,
    const int* __restrict__ rcv, const float* __restrict__ exbuf,
    const float* __restrict__ denom, float* __restrict__ out) {
    const int l = threadIdx.x & 63;
    const int wid = (blockIdx.x << 2) + (threadIdx.x >> 6);
    const int nW = gridDim.x << 2;
    const int h0 = l >> 4, h1 = 4 + (l >> 4);
    for (int g = wid; g < NE / 8; g += nW) {
        const int e0 = g * 8;
        #pragma unroll
        for (int i = 0; i < 8; ++i) {
            const int e = e0 + i;
            const int s = snd[e], r = rcv[e];
            float w0 = exbuf[(size_t)e * NH + h0] / denom[(size_t)r * NH + h0];
            float w1 = exbuf[(size_t)e * NH + h1] / denom[(size_t)r * NH + h1];
            float hs0 = hbuf[(size_t)s * EMB + l];
            float hs1 = hbuf[(size_t)s * EMB + l + 64];
            atomicAdd(&out[(size_t)r * EMB + l], w0 * hs0);
            atomicAdd(&out[(size_t)r * EMB + l + 64], w1 * hs1);
        }
    }
}

extern "C" void kernel_launch(void* const* d_in, const int* in_sizes, int n_in,
                              void* d_out, int out_size, void* d_ws, size_t ws_size,
                              hipStream_t stream) {
    const float* X   = (const float*)d_in[0];
    const float* EF  = (const float*)d_in[1];
    const float* W   = (const float*)d_in[2];
    const float* Wb  = (const float*)d_in[3];
    const float* We  = (const float*)d_in[4];
    const float* Web = (const float*)d_in[5];
    const float* Av  = (const float*)d_in[6];
    const int* snd   = (const int*)d_in[7];
    const int* rcv   = (const int*)d_in[8];
    float* out = (float*)d_out;

    char* ws = (char*)d_ws;
    float* hbuf  = (float*)ws;                                        // NN*EMB f32 = 25.6 MB
    float* exbuf = (float*)(ws + (size_t)NN * EMB * 4);               // NE*8 f32  = 25.6 MB
    float* denom = (float*)(ws + (size_t)NN * EMB * 4 + (size_t)NE * NH * 4); // NN*8 = 1.6 MB

    // accumulated via atomics -> must zero every launch (replays don't re-poison)
    hipMemsetAsync(out, 0, (size_t)NN * EMB * sizeof(float), stream);
    hipMemsetAsync(denom, 0, (size_t)NN * NH * sizeof(float), stream);

    k_node_proj<<<(NN + 31) / 32, 256, 0, stream>>>(X, W, Wb, hbuf);
    k_edge_attn<<<1024, 256, 0, stream>>>(EF, We, Web, Av, hbuf, snd, rcv, exbuf, denom);
    k_scatter<<<1024, 256, 0, stream>>>(hbuf, snd, rcv, exbuf, denom, out);
}

// Round 2
// 594.606 us; speedup vs baseline: 1.9964x; 1.9964x over previous
//
#include <hip/hip_runtime.h>
#include <math.h>

#define NN 50000
#define NE 800000
#define IND 256
#define ED 64
#define EMB 128
#define NH 8
#define HD 16

typedef short bf16x8 __attribute__((ext_vector_type(8)));
typedef float f32x4 __attribute__((ext_vector_type(4)));

__device__ __forceinline__ unsigned short rne16(float f) {
    unsigned u = __float_as_uint(f);
    unsigned r = u + 0x7FFFu + ((u >> 16) & 1u);
    return (unsigned short)(r >> 16);
}

__device__ __forceinline__ float mishf(float v) {
    // mish(v) = v * ((1+e^v)^2 - 1) / ((1+e^v)^2 + 1)
    float t = __expf(fminf(v, 20.f));
    float u = 1.f + t;
    u = u * u;
    return v * (u - 1.f) * __builtin_amdgcn_rcpf(u + 1.f);
}

// ---------------- node projection: h = X @ W + b ---------------------------
__global__ __launch_bounds__(256) void k_node_proj(
    const float* __restrict__ X, const float* __restrict__ W,
    const float* __restrict__ b, float* __restrict__ hout) {
    __shared__ float As[32][32];
    __shared__ float Ws[32][128];
    const int row0 = blockIdx.x * 32;
    const int tid = threadIdx.x;
    const int col = (tid & 31) * 4;
    const int rb  = (tid >> 5) * 4;
    float acc[4][4] = {};
    for (int k0 = 0; k0 < IND; k0 += 32) {
        {
            int r = tid >> 5, kk = tid & 31;
            #pragma unroll
            for (int i = 0; i < 4; ++i) {
                int rr = r + i * 8;
                int gr = row0 + rr;
                As[rr][kk] = (gr < NN) ? X[(size_t)gr * IND + k0 + kk] : 0.f;
            }
        }
        {
            int j = tid & 127, kb = tid >> 7;
            #pragma unroll
            for (int i = 0; i < 16; ++i) {
                int kk = kb + i * 2;
                Ws[kk][j] = W[(size_t)(k0 + kk) * EMB + j];
            }
        }
        __syncthreads();
        #pragma unroll
        for (int kk = 0; kk < 32; ++kk) {
            float4 wv = *(const float4*)&Ws[kk][col];
            float av[4];
            #pragma unroll
            for (int r = 0; r < 4; ++r) av[r] = As[rb + r][kk];
            #pragma unroll
            for (int r = 0; r < 4; ++r) {
                acc[r][0] = fmaf(av[r], wv.x, acc[r][0]);
                acc[r][1] = fmaf(av[r], wv.y, acc[r][1]);
                acc[r][2] = fmaf(av[r], wv.z, acc[r][2]);
                acc[r][3] = fmaf(av[r], wv.w, acc[r][3]);
            }
        }
        __syncthreads();
    }
    #pragma unroll
    for (int r = 0; r < 4; ++r) {
        int gr = row0 + rb + r;
        if (gr < NN) {
            float4 o;
            o.x = acc[r][0] + b[col];
            o.y = acc[r][1] + b[col + 1];
            o.z = acc[r][2] + b[col + 2];
            o.w = acc[r][3] + b[col + 3];
            *(float4*)&hout[(size_t)gr * EMB + col] = o;
        }
    }
}

// ---------- fused edge pass: MFMA proj + gather + mish + logits + exp ------
// 1 wave = 16 edges. Split-bf16 (hi+lo) MFMA for fp32-grade accuracy.
__global__ __launch_bounds__(256) void k_edge_attn(
    const float* __restrict__ EF, const float* __restrict__ We,
    const float* __restrict__ Web, const float* __restrict__ Av,
    const float* __restrict__ hbuf, const int* __restrict__ snd,
    const int* __restrict__ rcv, float* __restrict__ exbuf,
    float* __restrict__ denom) {
    // B fragments staged in exact per-lane MFMA order: [c*2+kk][lane] x 8 bf16
    __shared__ bf16x8 BH[1024];
    __shared__ bf16x8 BL[1024];
    for (int t = threadIdx.x; t < 1024; t += 256) {
        int ckk = t >> 6;                 // chunk*2+kk
        int lane = t & 63;
        int colg = (ckk >> 1) * 16 + (lane & 15);
        int kb = (ckk & 1) * 32 + (lane >> 4) * 8;
        bf16x8 vh, vl;
        #pragma unroll
        for (int j = 0; j < 8; ++j) {
            float f = We[(size_t)(kb + j) * EMB + colg];
            unsigned short hb = rne16(f);
            float fh = __uint_as_float((unsigned)hb << 16);
            vh[j] = (short)hb;
            vl[j] = (short)rne16(f - fh);
        }
        BH[t] = vh;
        BL[t] = vl;
    }
    __syncthreads();

    const int l = threadIdx.x & 63;
    const int lanecol = l & 15;
    const int q = l >> 4;
    const int wid = (blockIdx.x << 2) + (threadIdx.x >> 6);
    const int nW = gridDim.x << 2;

    float web[8], av[8];
    #pragma unroll
    for (int c = 0; c < 8; ++c) {
        web[c] = Web[c * 16 + lanecol];
        av[c]  = Av[c * 16 + lanecol];
    }

    const int NT = NE / 16;
    for (int tIdx = wid; tIdx < NT; tIdx += nW) {
        const int e0 = tIdx * 16;
        // ---- A fragments: EF rows e0..e0+15, split hi/lo bf16 ----
        const float* ar = EF + (size_t)(e0 + lanecol) * ED + q * 8;
        float fa[16];
        *(float4*)&fa[0]  = *(const float4*)ar;
        *(float4*)&fa[4]  = *(const float4*)(ar + 4);
        *(float4*)&fa[8]  = *(const float4*)(ar + 32);
        *(float4*)&fa[12] = *(const float4*)(ar + 36);
        bf16x8 ahi[2], alo[2];
        #pragma unroll
        for (int kk = 0; kk < 2; ++kk) {
            #pragma unroll
            for (int j = 0; j < 8; ++j) {
                float f = fa[kk * 8 + j];
                unsigned short hb = rne16(f);
                float fh = __uint_as_float((unsigned)hb << 16);
                ahi[kk][j] = (short)hb;
                alo[kk][j] = (short)rne16(f - fh);
            }
        }
        // ---- MFMA: acc[c] = EF @ We  (cols c*16..c*16+15) ----
        f32x4 acc[8];
        #pragma unroll
        for (int c = 0; c < 8; ++c) acc[c] = (f32x4){0.f, 0.f, 0.f, 0.f};
        #pragma unroll
        for (int c = 0; c < 8; ++c) {
            #pragma unroll
            for (int kk = 0; kk < 2; ++kk) {
                bf16x8 bh = BH[(c * 2 + kk) * 64 + l];
                bf16x8 bl = BL[(c * 2 + kk) * 64 + l];
                acc[c] = __builtin_amdgcn_mfma_f32_16x16x32_bf16(ahi[kk], bh, acc[c], 0, 0, 0);
                acc[c] = __builtin_amdgcn_mfma_f32_16x16x32_bf16(alo[kk], bh, acc[c], 0, 0, 0);
                acc[c] = __builtin_amdgcn_mfma_f32_16x16x32_bf16(ahi[kk], bl, acc[c], 0, 0, 0);
            }
        }
        // ---- epilogue: gather h, mish, per-head dot, exp, denom ----
        #pragma unroll
        for (int r = 0; r < 4; ++r) {
            const int e = e0 + q * 4 + r;
            const int s = snd[e], rn = rcv[e];
            const float* hs = hbuf + (size_t)s * EMB + lanecol;
            const float* hr = hbuf + (size_t)rn * EMB + lanecol;
            float p[8];
            #pragma unroll
            for (int c = 0; c < 8; ++c) {
                float v = acc[c][r] + web[c] + hs[c * 16] + hr[c * 16];
                p[c] = mishf(v) * av[c];
            }
            #pragma unroll
            for (int c = 0; c < 8; ++c) {
                #pragma unroll
                for (int off = 1; off < 16; off <<= 1)
                    p[c] += __shfl_xor(p[c], off, 16);
            }
            float myp = p[0];
            #pragma unroll
            for (int c = 1; c < 8; ++c) myp = (lanecol == c) ? p[c] : myp;
            if (lanecol < 8) {
                float ex = __expf(myp);
                exbuf[(size_t)e * NH + lanecol] = ex;
                atomicAdd(&denom[(size_t)rn * NH + lanecol], ex);
            }
        }
    }
}

// --------- pass C: weights = ex/denom[r]; out[r] += w * h[s] (atomics) -----
__global__ __launch_bounds__(256) void k_scatter(
    const float* __restrict__ hbuf, const int* __restrict__ snd,
    const int* __restrict__ rcv, const float* __restrict__ exbuf,
    const float* __restrict__ denom, float* __restrict__ out) {
    const int l = threadIdx.x & 63;
    const int wid = (blockIdx.x << 2) + (threadIdx.x >> 6);
    const int nW = gridDim.x << 2;
    const int h0 = l >> 4, h1 = 4 + (l >> 4);
    for (int g = wid; g < NE / 8; g += nW) {
        const int e0 = g * 8;
        #pragma unroll
        for (int i = 0; i < 8; ++i) {
            const int e = e0 + i;
            const int s = snd[e], r = rcv[e];
            float w0 = exbuf[(size_t)e * NH + h0] *
                       __builtin_amdgcn_rcpf(denom[(size_t)r * NH + h0]);
            float w1 = exbuf[(size_t)e * NH + h1] *
                       __builtin_amdgcn_rcpf(denom[(size_t)r * NH + h1]);
            float hs0 = hbuf[(size_t)s * EMB + l];
            float hs1 = hbuf[(size_t)s * EMB + l + 64];
            atomicAdd(&out[(size_t)r * EMB + l], w0 * hs0);
            atomicAdd(&out[(size_t)r * EMB + l + 64], w1 * hs1);
        }
    }
}

extern "C" void kernel_launch(void* const* d_in, const int* in_sizes, int n_in,
                              void* d_out, int out_size, void* d_ws, size_t ws_size,
                              hipStream_t stream) {
    const float* X   = (const float*)d_in[0];
    const float* EF  = (const float*)d_in[1];
    const float* W   = (const float*)d_in[2];
    const float* Wb  = (const float*)d_in[3];
    const float* We  = (const float*)d_in[4];
    const float* Web = (const float*)d_in[5];
    const float* Av  = (const float*)d_in[6];
    const int* snd   = (const int*)d_in[7];
    const int* rcv   = (const int*)d_in[8];
    float* out = (float*)d_out;

    char* ws = (char*)d_ws;
    float* hbuf  = (float*)ws;                                        // 25.6 MB
    float* exbuf = (float*)(ws + (size_t)NN * EMB * 4);               // 25.6 MB
    float* denom = (float*)(ws + (size_t)NN * EMB * 4 + (size_t)NE * NH * 4); // 1.6 MB

    hipMemsetAsync(out, 0, (size_t)NN * EMB * sizeof(float), stream);
    hipMemsetAsync(denom, 0, (size_t)NN * NH * sizeof(float), stream);

    k_node_proj<<<(NN + 31) / 32, 256, 0, stream>>>(X, W, Wb, hbuf);
    k_edge_attn<<<1024, 256, 0, stream>>>(EF, We, Web, Av, hbuf, snd, rcv, exbuf, denom);
    k_scatter<<<1024, 256, 0, stream>>>(hbuf, snd, rcv, exbuf, denom, out);
}

// Round 3
// 586.437 us; speedup vs baseline: 2.0242x; 1.0139x over previous
//
#include <hip/hip_runtime.h>
#include <math.h>

#define NN 50000
#define NE 800000
#define IND 256
#define ED 64
#define EMB 128
#define NH 8
#define HD 16

typedef short bf16x8 __attribute__((ext_vector_type(8)));
typedef float f32x4 __attribute__((ext_vector_type(4)));

__device__ __forceinline__ unsigned short rne16(float f) {
    unsigned u = __float_as_uint(f);
    unsigned r = u + 0x7FFFu + ((u >> 16) & 1u);
    return (unsigned short)(r >> 16);
}

__device__ __forceinline__ float mishf(float v) {
    float t = __expf(fminf(v, 20.f));
    float u = 1.f + t;
    u = u * u;
    return v * (u - 1.f) * __builtin_amdgcn_rcpf(u + 1.f);
}

// ---------------- node projection: h = X @ W + b ---------------------------
__global__ __launch_bounds__(256) void k_node_proj(
    const float* __restrict__ X, const float* __restrict__ W,
    const float* __restrict__ b, float* __restrict__ hout) {
    __shared__ float As[32][32];
    __shared__ float Ws[32][128];
    const int row0 = blockIdx.x * 32;
    const int tid = threadIdx.x;
    const int col = (tid & 31) * 4;
    const int rb  = (tid >> 5) * 4;
    float acc[4][4] = {};
    for (int k0 = 0; k0 < IND; k0 += 32) {
        {
            int r = tid >> 5, kk = tid & 31;
            #pragma unroll
            for (int i = 0; i < 4; ++i) {
                int rr = r + i * 8;
                int gr = row0 + rr;
                As[rr][kk] = (gr < NN) ? X[(size_t)gr * IND + k0 + kk] : 0.f;
            }
        }
        {
            int j = tid & 127, kb = tid >> 7;
            #pragma unroll
            for (int i = 0; i < 16; ++i) {
                int kk = kb + i * 2;
                Ws[kk][j] = W[(size_t)(k0 + kk) * EMB + j];
            }
        }
        __syncthreads();
        #pragma unroll
        for (int kk = 0; kk < 32; ++kk) {
            float4 wv = *(const float4*)&Ws[kk][col];
            float av[4];
            #pragma unroll
            for (int r = 0; r < 4; ++r) av[r] = As[rb + r][kk];
            #pragma unroll
            for (int r = 0; r < 4; ++r) {
                acc[r][0] = fmaf(av[r], wv.x, acc[r][0]);
                acc[r][1] = fmaf(av[r], wv.y, acc[r][1]);
                acc[r][2] = fmaf(av[r], wv.z, acc[r][2]);
                acc[r][3] = fmaf(av[r], wv.w, acc[r][3]);
            }
        }
        __syncthreads();
    }
    #pragma unroll
    for (int r = 0; r < 4; ++r) {
        int gr = row0 + rb + r;
        if (gr < NN) {
            float4 o;
            o.x = acc[r][0] + b[col];
            o.y = acc[r][1] + b[col + 1];
            o.z = acc[r][2] + b[col + 2];
            o.w = acc[r][3] + b[col + 3];
            *(float4*)&hout[(size_t)gr * EMB + col] = o;
        }
    }
}

// ---------------- CSR build: hist -> scan -> bucket ------------------------
__global__ __launch_bounds__(256) void k_hist(const int* __restrict__ rcv,
                                              int* __restrict__ cnt) {
    int e = blockIdx.x * 256 + threadIdx.x;
    if (e < NE) atomicAdd(&cnt[rcv[e]], 1);
}

// single block, 1024 threads; cursor may alias cnt (reads cnt before write)
__global__ __launch_bounds__(1024) void k_scan(const int* __restrict__ cnt,
                                               int* __restrict__ rowptr,
                                               int* __restrict__ cursor) {
    __shared__ int part[1024];
    const int t = threadIdx.x;
    const int CH = (NN + 1023) / 1024;
    const int base = t * CH;
    int s = 0;
    for (int i = 0; i < CH; ++i) {
        int idx = base + i;
        if (idx < NN) s += cnt[idx];
    }
    part[t] = s;
    __syncthreads();
    for (int off = 1; off < 1024; off <<= 1) {
        int v = (t >= off) ? part[t - off] : 0;
        __syncthreads();
        part[t] += v;
        __syncthreads();
    }
    int run = (t > 0) ? part[t - 1] : 0;
    for (int i = 0; i < CH; ++i) {
        int idx = base + i;
        if (idx < NN) {
            int c = cnt[idx];
            rowptr[idx] = run;
            cursor[idx] = run;
            run += c;
        }
    }
    if (t == 1023) rowptr[NN] = run;
}

__global__ __launch_bounds__(256) void k_bucket(
    const int* __restrict__ snd, const int* __restrict__ rcv,
    int* __restrict__ cursor, int* __restrict__ csr_snd,
    int* __restrict__ csr_pos) {
    int e = blockIdx.x * 256 + threadIdx.x;
    if (e < NE) {
        int pos = atomicAdd(&cursor[rcv[e]], 1);
        csr_snd[pos] = snd[e];
        csr_pos[e] = pos;
    }
}

// ---------- fused edge pass: MFMA proj + gather + mish + logits + exp ------
__global__ __launch_bounds__(256) void k_edge_attn(
    const float* __restrict__ EF, const float* __restrict__ We,
    const float* __restrict__ Web, const float* __restrict__ Av,
    const float* __restrict__ hbuf, const int* __restrict__ snd,
    const int* __restrict__ rcv, const int* __restrict__ csr_pos,
    float* __restrict__ ex_csr) {
    __shared__ bf16x8 BH[1024];
    __shared__ bf16x8 BL[1024];
    for (int t = threadIdx.x; t < 1024; t += 256) {
        int ckk = t >> 6;
        int lane = t & 63;
        int colg = (ckk >> 1) * 16 + (lane & 15);
        int kb = (ckk & 1) * 32 + (lane >> 4) * 8;
        bf16x8 vh, vl;
        #pragma unroll
        for (int j = 0; j < 8; ++j) {
            float f = We[(size_t)(kb + j) * EMB + colg];
            unsigned short hb = rne16(f);
            float fh = __uint_as_float((unsigned)hb << 16);
            vh[j] = (short)hb;
            vl[j] = (short)rne16(f - fh);
        }
        BH[t] = vh;
        BL[t] = vl;
    }
    __syncthreads();

    const int l = threadIdx.x & 63;
    const int lanecol = l & 15;
    const int q = l >> 4;
    const int wid = (blockIdx.x << 2) + (threadIdx.x >> 6);
    const int nW = gridDim.x << 2;

    float web[8], av[8];
    #pragma unroll
    for (int c = 0; c < 8; ++c) {
        web[c] = Web[c * 16 + lanecol];
        av[c]  = Av[c * 16 + lanecol];
    }

    const int NT = NE / 16;
    for (int tIdx = wid; tIdx < NT; tIdx += nW) {
        const int e0 = tIdx * 16;
        const float* ar = EF + (size_t)(e0 + lanecol) * ED + q * 8;
        float fa[16];
        *(float4*)&fa[0]  = *(const float4*)ar;
        *(float4*)&fa[4]  = *(const float4*)(ar + 4);
        *(float4*)&fa[8]  = *(const float4*)(ar + 32);
        *(float4*)&fa[12] = *(const float4*)(ar + 36);
        bf16x8 ahi[2], alo[2];
        #pragma unroll
        for (int kk = 0; kk < 2; ++kk) {
            #pragma unroll
            for (int j = 0; j < 8; ++j) {
                float f = fa[kk * 8 + j];
                unsigned short hb = rne16(f);
                float fh = __uint_as_float((unsigned)hb << 16);
                ahi[kk][j] = (short)hb;
                alo[kk][j] = (short)rne16(f - fh);
            }
        }
        f32x4 acc[8];
        #pragma unroll
        for (int c = 0; c < 8; ++c) acc[c] = (f32x4){0.f, 0.f, 0.f, 0.f};
        #pragma unroll
        for (int c = 0; c < 8; ++c) {
            #pragma unroll
            for (int kk = 0; kk < 2; ++kk) {
                bf16x8 bh = BH[(c * 2 + kk) * 64 + l];
                bf16x8 bl = BL[(c * 2 + kk) * 64 + l];
                acc[c] = __builtin_amdgcn_mfma_f32_16x16x32_bf16(ahi[kk], bh, acc[c], 0, 0, 0);
                acc[c] = __builtin_amdgcn_mfma_f32_16x16x32_bf16(alo[kk], bh, acc[c], 0, 0, 0);
                acc[c] = __builtin_amdgcn_mfma_f32_16x16x32_bf16(ahi[kk], bl, acc[c], 0, 0, 0);
            }
        }
        #pragma unroll
        for (int r = 0; r < 4; ++r) {
            const int e = e0 + q * 4 + r;
            const int s = snd[e], rn = rcv[e];
            const int pos = csr_pos[e];
            const float* hs = hbuf + (size_t)s * EMB + lanecol;
            const float* hr = hbuf + (size_t)rn * EMB + lanecol;
            float p[8];
            #pragma unroll
            for (int c = 0; c < 8; ++c) {
                float v = acc[c][r] + web[c] + hs[c * 16] + hr[c * 16];
                p[c] = mishf(v) * av[c];
            }
            #pragma unroll
            for (int c = 0; c < 8; ++c) {
                #pragma unroll
                for (int off = 1; off < 16; off <<= 1)
                    p[c] += __shfl_xor(p[c], off, 16);
            }
            float myp = p[0];
            #pragma unroll
            for (int c = 1; c < 8; ++c) myp = (lanecol == c) ? p[c] : myp;
            if (lanecol < 8) {
                ex_csr[(size_t)pos * NH + lanecol] = __expf(myp);
            }
        }
    }
}

// --------- segmented aggregation: one wave per node, no atomics ------------
__global__ __launch_bounds__(256) void k_agg(
    const float* __restrict__ hbuf, const int* __restrict__ csr_snd,
    const float* __restrict__ ex_csr, const int* __restrict__ rowptr,
    float* __restrict__ out) {
    const int l = threadIdx.x & 63;
    const int node = blockIdx.x * 4 + (threadIdx.x >> 6);
    if (node >= NN) return;
    const int beg = rowptr[node], end = rowptr[node + 1];
    const int h0 = l >> 4, h1 = 4 + (l >> 4);
    float acc0 = 0.f, acc1 = 0.f, den0 = 0.f, den1 = 0.f;
    int s = (beg < end) ? csr_snd[beg] : 0;
    for (int j = beg; j < end; ++j) {
        int snext = (j + 1 < end) ? csr_snd[j + 1] : 0;   // prefetch next sender
        float ex0 = ex_csr[(size_t)j * NH + h0];
        float ex1 = ex_csr[(size_t)j * NH + h1];
        const float* hp = hbuf + (size_t)s * EMB;
        float hs0 = hp[l];
        float hs1 = hp[l + 64];
        acc0 = fmaf(ex0, hs0, acc0);
        acc1 = fmaf(ex1, hs1, acc1);
        den0 += ex0;
        den1 += ex1;
        s = snext;
    }
    float o0 = (end > beg) ? acc0 / den0 : 0.f;
    float o1 = (end > beg) ? acc1 / den1 : 0.f;
    out[(size_t)node * EMB + l] = o0;
    out[(size_t)node * EMB + l + 64] = o1;
}

extern "C" void kernel_launch(void* const* d_in, const int* in_sizes, int n_in,
                              void* d_out, int out_size, void* d_ws, size_t ws_size,
                              hipStream_t stream) {
    const float* X   = (const float*)d_in[0];
    const float* EF  = (const float*)d_in[1];
    const float* W   = (const float*)d_in[2];
    const float* Wb  = (const float*)d_in[3];
    const float* We  = (const float*)d_in[4];
    const float* Web = (const float*)d_in[5];
    const float* Av  = (const float*)d_in[6];
    const int* snd   = (const int*)d_in[7];
    const int* rcv   = (const int*)d_in[8];
    float* out = (float*)d_out;

    char* ws = (char*)d_ws;
    size_t off = 0;
    float* hbuf   = (float*)(ws + off); off += (size_t)NN * EMB * 4;   // 25.6 MB
    float* ex_csr = (float*)(ws + off); off += (size_t)NE * NH * 4;    // 25.6 MB
    int* csr_snd  = (int*)(ws + off);   off += (size_t)NE * 4;         // 3.2 MB
    int* csr_pos  = (int*)(ws + off);   off += (size_t)NE * 4;         // 3.2 MB
    int* rowptr   = (int*)(ws + off);   off += (size_t)(NN + 1) * 4;
    int* cursor   = (int*)(ws + off);   off += (size_t)NN * 4;
    int* cnt      = cursor;             // aliased: k_scan reads cnt[idx] before writing cursor[idx]

    // counting sort needs zeroed histogram each launch
    hipMemsetAsync(cnt, 0, (size_t)NN * sizeof(int), stream);

    k_node_proj<<<(NN + 31) / 32, 256, 0, stream>>>(X, W, Wb, hbuf);
    k_hist<<<NE / 256, 256, 0, stream>>>(rcv, cnt);
    k_scan<<<1, 1024, 0, stream>>>(cnt, rowptr, cursor);
    k_bucket<<<NE / 256, 256, 0, stream>>>(snd, rcv, cursor, csr_snd, csr_pos);
    k_edge_attn<<<1024, 256, 0, stream>>>(EF, We, Web, Av, hbuf, snd, rcv, csr_pos, ex_csr);
    k_agg<<<(NN + 3) / 4, 256, 0, stream>>>(hbuf, csr_snd, ex_csr, rowptr, out);
}

// Round 4
// 531.508 us; speedup vs baseline: 2.2334x; 1.1033x over previous
//
#include <hip/hip_runtime.h>
#include <math.h>

#define NN 50000
#define NE 800000
#define IND 256
#define ED 64
#define EMB 128
#define NH 8
#define HD 16

typedef short bf16x8 __attribute__((ext_vector_type(8)));
typedef float f32x4 __attribute__((ext_vector_type(4)));

__device__ __forceinline__ unsigned short rne16(float f) {
    unsigned u = __float_as_uint(f);
    unsigned r = u + 0x7FFFu + ((u >> 16) & 1u);
    return (unsigned short)(r >> 16);
}

__device__ __forceinline__ float mishf(float v) {
    float t = __expf(fminf(v, 20.f));
    float u = 1.f + t;
    u = u * u;
    return v * (u - 1.f) * __builtin_amdgcn_rcpf(u + 1.f);
}

// ---------------- node projection: h = X @ W + b ---------------------------
__global__ __launch_bounds__(256) void k_node_proj(
    const float* __restrict__ X, const float* __restrict__ W,
    const float* __restrict__ b, float* __restrict__ hout) {
    __shared__ float As[32][32];
    __shared__ float Ws[32][128];
    const int row0 = blockIdx.x * 32;
    const int tid = threadIdx.x;
    const int col = (tid & 31) * 4;
    const int rb  = (tid >> 5) * 4;
    float acc[4][4] = {};
    for (int k0 = 0; k0 < IND; k0 += 32) {
        {
            int r = tid >> 5, kk = tid & 31;
            #pragma unroll
            for (int i = 0; i < 4; ++i) {
                int rr = r + i * 8;
                int gr = row0 + rr;
                As[rr][kk] = (gr < NN) ? X[(size_t)gr * IND + k0 + kk] : 0.f;
            }
        }
        {
            int j = tid & 127, kb = tid >> 7;
            #pragma unroll
            for (int i = 0; i < 16; ++i) {
                int kk = kb + i * 2;
                Ws[kk][j] = W[(size_t)(k0 + kk) * EMB + j];
            }
        }
        __syncthreads();
        #pragma unroll
        for (int kk = 0; kk < 32; ++kk) {
            float4 wv = *(const float4*)&Ws[kk][col];
            float av[4];
            #pragma unroll
            for (int r = 0; r < 4; ++r) av[r] = As[rb + r][kk];
            #pragma unroll
            for (int r = 0; r < 4; ++r) {
                acc[r][0] = fmaf(av[r], wv.x, acc[r][0]);
                acc[r][1] = fmaf(av[r], wv.y, acc[r][1]);
                acc[r][2] = fmaf(av[r], wv.z, acc[r][2]);
                acc[r][3] = fmaf(av[r], wv.w, acc[r][3]);
            }
        }
        __syncthreads();
    }
    #pragma unroll
    for (int r = 0; r < 4; ++r) {
        int gr = row0 + rb + r;
        if (gr < NN) {
            float4 o;
            o.x = acc[r][0] + b[col];
            o.y = acc[r][1] + b[col + 1];
            o.z = acc[r][2] + b[col + 2];
            o.w = acc[r][3] + b[col + 3];
            *(float4*)&hout[(size_t)gr * EMB + col] = o;
        }
    }
}

// ---------------- CSR build ------------------------------------------------
__global__ __launch_bounds__(256) void k_hist(const int* __restrict__ rcv,
                                              int* __restrict__ cnt) {
    int e = blockIdx.x * 256 + threadIdx.x;
    if (e < NE) atomicAdd(&cnt[rcv[e]], 1);
}

// per-block inclusive scan (coalesced); rowptr gets intra-block EXCLUSIVE scan
__global__ __launch_bounds__(512) void k_part(const int* __restrict__ cnt,
                                              int* __restrict__ rowptr,
                                              int* __restrict__ part) {
    __shared__ int sm[512];
    const int t = threadIdx.x;
    const int idx = blockIdx.x * 512 + t;
    int v = (idx < NN) ? cnt[idx] : 0;
    sm[t] = v;
    __syncthreads();
    #pragma unroll
    for (int off = 1; off < 512; off <<= 1) {
        int y = (t >= off) ? sm[t - off] : 0;
        __syncthreads();
        sm[t] += y;
        __syncthreads();
    }
    if (idx < NN) rowptr[idx] = sm[t] - v;   // exclusive within block
    if (t == 511) part[blockIdx.x] = sm[511];
}

// scan the 98 block-partials (single small block)
__global__ __launch_bounds__(128) void k_scan2(const int* __restrict__ part,
                                               int* __restrict__ partoff,
                                               int* __restrict__ rowptr) {
    __shared__ int sm[128];
    const int t = threadIdx.x;
    const int NB = (NN + 511) / 512;
    int v = (t < NB) ? part[t] : 0;
    sm[t] = v;
    __syncthreads();
    #pragma unroll
    for (int off = 1; off < 128; off <<= 1) {
        int y = (t >= off) ? sm[t - off] : 0;
        __syncthreads();
        sm[t] += y;
        __syncthreads();
    }
    if (t < NB) partoff[t] = sm[t] - v;      // exclusive
    if (t == 0) rowptr[NN] = NE;
}

__global__ __launch_bounds__(512) void k_fix(int* __restrict__ rowptr,
                                             const int* __restrict__ partoff,
                                             int* __restrict__ cursor) {
    const int idx = blockIdx.x * 512 + threadIdx.x;
    if (idx < NN) {
        int r = rowptr[idx] + partoff[blockIdx.x];
        rowptr[idx] = r;
        cursor[idx] = r;
    }
}

__global__ __launch_bounds__(256) void k_bucket(
    const int* __restrict__ snd, const int* __restrict__ rcv,
    int* __restrict__ cursor, int* __restrict__ csr_snd,
    int* __restrict__ csr_eid) {
    int e = blockIdx.x * 256 + threadIdx.x;
    if (e < NE) {
        int pos = atomicAdd(&cursor[rcv[e]], 1);
        csr_snd[pos] = snd[e];
        csr_eid[pos] = e;
    }
}

// ---------- fused edge pass, CSR order -------------------------------------
// Column permutation: chunk c, lane j -> EMB col j*8+c  (lane owns 8
// consecutive cols). Head = lane pair (2h, 2h+1); reduce = one shfl_xor(1).
#define LOAD_FA(dst, base)                                        \
    {                                                             \
        const float* ar_ = (base);                                \
        *(float4*)&dst[0]  = *(const float4*)ar_;                 \
        *(float4*)&dst[4]  = *(const float4*)(ar_ + 4);           \
        *(float4*)&dst[8]  = *(const float4*)(ar_ + 32);          \
        *(float4*)&dst[12] = *(const float4*)(ar_ + 36);          \
    }

__global__ __launch_bounds__(256) void k_edge_attn(
    const float* __restrict__ EF, const float* __restrict__ We,
    const float* __restrict__ Web, const float* __restrict__ Av,
    const float* __restrict__ hbuf, const int* __restrict__ snd,
    const int* __restrict__ rcv, const int* __restrict__ csr_eid,
    float* __restrict__ ex_csr) {
    __shared__ bf16x8 BH[1024];
    __shared__ bf16x8 BL[1024];
    for (int t = threadIdx.x; t < 1024; t += 256) {
        int ckk = t >> 6;
        int lane = t & 63;
        int c = ckk >> 1;
        int colg = (lane & 15) * 8 + c;            // permuted column
        int kb = (ckk & 1) * 32 + (lane >> 4) * 8;
        bf16x8 vh, vl;
        #pragma unroll
        for (int j = 0; j < 8; ++j) {
            float f = We[(size_t)(kb + j) * EMB + colg];
            unsigned short hb = rne16(f);
            float fh = __uint_as_float((unsigned)hb << 16);
            vh[j] = (short)hb;
            vl[j] = (short)rne16(f - fh);
        }
        BH[t] = vh;
        BL[t] = vl;
    }
    __syncthreads();

    const int l = threadIdx.x & 63;
    const int lanecol = l & 15;
    const int q = l >> 4;
    const int wid = (blockIdx.x << 2) + (threadIdx.x >> 6);
    const int nW = gridDim.x << 2;

    // per-lane cols lanecol*8 .. +7 : contiguous float4 pairs
    float4 wbv0 = *(const float4*)&Web[lanecol * 8];
    float4 wbv1 = *(const float4*)&Web[lanecol * 8 + 4];
    float4 avv0 = *(const float4*)&Av[lanecol * 8];
    float4 avv1 = *(const float4*)&Av[lanecol * 8 + 4];
    float web[8] = {wbv0.x, wbv0.y, wbv0.z, wbv0.w, wbv1.x, wbv1.y, wbv1.z, wbv1.w};
    float av[8]  = {avv0.x, avv0.y, avv0.z, avv0.w, avv1.x, avv1.y, avv1.z, avv1.w};

    const int NT = NE / 16;
    int tIdx = wid;
    if (tIdx >= NT) return;
    int eid = csr_eid[tIdx * 16 + lanecol];
    float fa[16];
    LOAD_FA(fa, EF + (size_t)eid * ED + q * 8);

    while (true) {
        const int tNext = tIdx + nW;
        const bool more = (tNext < NT);
        int eid_next = 0;
        if (more) eid_next = csr_eid[tNext * 16 + lanecol];

        // convert current A to split-bf16 fragments
        bf16x8 ahi[2], alo[2];
        #pragma unroll
        for (int kk = 0; kk < 2; ++kk) {
            #pragma unroll
            for (int j = 0; j < 8; ++j) {
                float f = fa[kk * 8 + j];
                unsigned short hb = rne16(f);
                float fh = __uint_as_float((unsigned)hb << 16);
                ahi[kk][j] = (short)hb;
                alo[kk][j] = (short)rne16(f - fh);
            }
        }
        f32x4 acc[8];
        #pragma unroll
        for (int c = 0; c < 8; ++c) acc[c] = (f32x4){0.f, 0.f, 0.f, 0.f};
        #pragma unroll
        for (int c = 0; c < 8; ++c) {
            #pragma unroll
            for (int kk = 0; kk < 2; ++kk) {
                bf16x8 bh = BH[(c * 2 + kk) * 64 + l];
                bf16x8 bl = BL[(c * 2 + kk) * 64 + l];
                acc[c] = __builtin_amdgcn_mfma_f32_16x16x32_bf16(ahi[kk], bh, acc[c], 0, 0, 0);
                acc[c] = __builtin_amdgcn_mfma_f32_16x16x32_bf16(alo[kk], bh, acc[c], 0, 0, 0);
                acc[c] = __builtin_amdgcn_mfma_f32_16x16x32_bf16(ahi[kk], bl, acc[c], 0, 0, 0);
            }
        }

        // prefetch next tile's EF rows under the epilogue
        float fan[16];
        if (more) LOAD_FA(fan, EF + (size_t)eid_next * ED + q * 8);

        // epilogue: 4 edges per q-group
        #pragma unroll
        for (int r = 0; r < 4; ++r) {
            const int pos = tIdx * 16 + (q << 2) + r;
            const int ee = __shfl(eid, (q << 2) + r, 16);
            const int s = snd[ee], rn = rcv[ee];
            const float* hs = hbuf + (size_t)s * EMB + lanecol * 8;
            const float* hr = hbuf + (size_t)rn * EMB + lanecol * 8;
            float4 hs0 = *(const float4*)hs;
            float4 hs1 = *(const float4*)(hs + 4);
            float4 hr0 = *(const float4*)hr;
            float4 hr1 = *(const float4*)(hr + 4);
            float hsv[8] = {hs0.x, hs0.y, hs0.z, hs0.w, hs1.x, hs1.y, hs1.z, hs1.w};
            float hrv[8] = {hr0.x, hr0.y, hr0.z, hr0.w, hr1.x, hr1.y, hr1.z, hr1.w};
            float pp = 0.f;
            #pragma unroll
            for (int c = 0; c < 8; ++c) {
                float v = acc[c][r] + web[c] + hsv[c] + hrv[c];
                pp = fmaf(mishf(v), av[c], pp);
            }
            pp += __shfl_xor(pp, 1, 16);     // head = lane pair
            if ((lanecol & 1) == 0) {
                ex_csr[(size_t)pos * NH + (lanecol >> 1)] = __expf(pp);
            }
        }

        if (!more) break;
        tIdx = tNext;
        eid = eid_next;
        #pragma unroll
        for (int i = 0; i < 16; ++i) fa[i] = fan[i];
    }
}

// --------- segmented aggregation: one wave per node, no atomics ------------
__global__ __launch_bounds__(256) void k_agg(
    const float* __restrict__ hbuf, const int* __restrict__ csr_snd,
    const float* __restrict__ ex_csr, const int* __restrict__ rowptr,
    float* __restrict__ out) {
    const int l = threadIdx.x & 63;
    const int node = blockIdx.x * 4 + (threadIdx.x >> 6);
    if (node >= NN) return;
    const int beg = rowptr[node], end = rowptr[node + 1];
    const int h0 = l >> 4, h1 = 4 + (l >> 4);
    float acc0 = 0.f, acc1 = 0.f, den0 = 0.f, den1 = 0.f;
    int s = (beg < end) ? csr_snd[beg] : 0;
    for (int j = beg; j < end; ++j) {
        int snext = (j + 1 < end) ? csr_snd[j + 1] : 0;
        float ex0 = ex_csr[(size_t)j * NH + h0];
        float ex1 = ex_csr[(size_t)j * NH + h1];
        const float* hp = hbuf + (size_t)s * EMB;
        float hs0 = hp[l];
        float hs1 = hp[l + 64];
        acc0 = fmaf(ex0, hs0, acc0);
        acc1 = fmaf(ex1, hs1, acc1);
        den0 += ex0;
        den1 += ex1;
        s = snext;
    }
    float o0 = (end > beg) ? acc0 / den0 : 0.f;
    float o1 = (end > beg) ? acc1 / den1 : 0.f;
    out[(size_t)node * EMB + l] = o0;
    out[(size_t)node * EMB + l + 64] = o1;
}

extern "C" void kernel_launch(void* const* d_in, const int* in_sizes, int n_in,
                              void* d_out, int out_size, void* d_ws, size_t ws_size,
                              hipStream_t stream) {
    const float* X   = (const float*)d_in[0];
    const float* EF  = (const float*)d_in[1];
    const float* W   = (const float*)d_in[2];
    const float* Wb  = (const float*)d_in[3];
    const float* We  = (const float*)d_in[4];
    const float* Web = (const float*)d_in[5];
    const float* Av  = (const float*)d_in[6];
    const int* snd   = (const int*)d_in[7];
    const int* rcv   = (const int*)d_in[8];
    float* out = (float*)d_out;

    char* ws = (char*)d_ws;
    size_t off = 0;
    float* hbuf   = (float*)(ws + off); off += (size_t)NN * EMB * 4;   // 25.6 MB
    float* ex_csr = (float*)(ws + off); off += (size_t)NE * NH * 4;    // 25.6 MB
    int* csr_snd  = (int*)(ws + off);   off += (size_t)NE * 4;         // 3.2 MB
    int* csr_eid  = (int*)(ws + off);   off += (size_t)NE * 4;         // 3.2 MB
    int* rowptr   = (int*)(ws + off);   off += (size_t)(NN + 1) * 4;
    int* cursor   = (int*)(ws + off);   off += (size_t)NN * 4;
    int* part     = (int*)(ws + off);   off += 512;
    int* partoff  = (int*)(ws + off);   off += 512;
    int* cnt      = cursor;  // alias: cnt consumed by k_part before k_fix writes cursor

    const int NB = (NN + 511) / 512;   // 98

    hipMemsetAsync(cnt, 0, (size_t)NN * sizeof(int), stream);
    k_node_proj<<<(NN + 31) / 32, 256, 0, stream>>>(X, W, Wb, hbuf);
    k_hist<<<NE / 256, 256, 0, stream>>>(rcv, cnt);
    k_part<<<NB, 512, 0, stream>>>(cnt, rowptr, part);
    k_scan2<<<1, 128, 0, stream>>>(part, partoff, rowptr);
    k_fix<<<NB, 512, 0, stream>>>(rowptr, partoff, cursor);
    k_bucket<<<NE / 256, 256, 0, stream>>>(snd, rcv, cursor, csr_snd, csr_eid);
    k_edge_attn<<<2048, 256, 0, stream>>>(EF, We, Web, Av, hbuf, snd, rcv, csr_eid, ex_csr);
    k_agg<<<(NN + 3) / 4, 256, 0, stream>>>(hbuf, csr_snd, ex_csr, rowptr, out);
}

// Round 5
// 474.955 us; speedup vs baseline: 2.4994x; 1.1191x over previous
//
#include <hip/hip_runtime.h>
#include <math.h>

#define NN 50000
#define NE 800000
#define IND 256
#define ED 64
#define EMB 128
#define NH 8
#define HD 16

typedef short bf16x8 __attribute__((ext_vector_type(8)));
typedef float f32x4 __attribute__((ext_vector_type(4)));

__device__ __forceinline__ unsigned short rne16(float f) {
    unsigned u = __float_as_uint(f);
    unsigned r = u + 0x7FFFu + ((u >> 16) & 1u);
    return (unsigned short)(r >> 16);
}

__device__ __forceinline__ float mishf(float v) {
    float t = __expf(fminf(v, 20.f));
    float u = 1.f + t;
    u = u * u;
    return v * (u - 1.f) * __builtin_amdgcn_rcpf(u + 1.f);
}

// ---------------- node projection: h = X @ W + b ---------------------------
__global__ __launch_bounds__(256) void k_node_proj(
    const float* __restrict__ X, const float* __restrict__ W,
    const float* __restrict__ b, float* __restrict__ hout) {
    __shared__ float As[32][32];
    __shared__ float Ws[32][128];
    const int row0 = blockIdx.x * 32;
    const int tid = threadIdx.x;
    const int col = (tid & 31) * 4;
    const int rb  = (tid >> 5) * 4;
    float acc[4][4] = {};
    for (int k0 = 0; k0 < IND; k0 += 32) {
        {
            int r = tid >> 5, kk = tid & 31;
            #pragma unroll
            for (int i = 0; i < 4; ++i) {
                int rr = r + i * 8;
                int gr = row0 + rr;
                As[rr][kk] = (gr < NN) ? X[(size_t)gr * IND + k0 + kk] : 0.f;
            }
        }
        {
            int j = tid & 127, kb = tid >> 7;
            #pragma unroll
            for (int i = 0; i < 16; ++i) {
                int kk = kb + i * 2;
                Ws[kk][j] = W[(size_t)(k0 + kk) * EMB + j];
            }
        }
        __syncthreads();
        #pragma unroll
        for (int kk = 0; kk < 32; ++kk) {
            float4 wv = *(const float4*)&Ws[kk][col];
            float av[4];
            #pragma unroll
            for (int r = 0; r < 4; ++r) av[r] = As[rb + r][kk];
            #pragma unroll
            for (int r = 0; r < 4; ++r) {
                acc[r][0] = fmaf(av[r], wv.x, acc[r][0]);
                acc[r][1] = fmaf(av[r], wv.y, acc[r][1]);
                acc[r][2] = fmaf(av[r], wv.z, acc[r][2]);
                acc[r][3] = fmaf(av[r], wv.w, acc[r][3]);
            }
        }
        __syncthreads();
    }
    #pragma unroll
    for (int r = 0; r < 4; ++r) {
        int gr = row0 + rb + r;
        if (gr < NN) {
            float4 o;
            o.x = acc[r][0] + b[col];
            o.y = acc[r][1] + b[col + 1];
            o.z = acc[r][2] + b[col + 2];
            o.w = acc[r][3] + b[col + 3];
            *(float4*)&hout[(size_t)gr * EMB + col] = o;
        }
    }
}

// ---------------- CSR build ------------------------------------------------
__global__ __launch_bounds__(256) void k_hist(const int* __restrict__ rcv,
                                              int* __restrict__ cnt) {
    int e = blockIdx.x * 256 + threadIdx.x;
    if (e < NE) atomicAdd(&cnt[rcv[e]], 1);
}

__global__ __launch_bounds__(512) void k_part(const int* __restrict__ cnt,
                                              int* __restrict__ rowptr,
                                              int* __restrict__ part) {
    __shared__ int sm[512];
    const int t = threadIdx.x;
    const int idx = blockIdx.x * 512 + t;
    int v = (idx < NN) ? cnt[idx] : 0;
    sm[t] = v;
    __syncthreads();
    #pragma unroll
    for (int off = 1; off < 512; off <<= 1) {
        int y = (t >= off) ? sm[t - off] : 0;
        __syncthreads();
        sm[t] += y;
        __syncthreads();
    }
    if (idx < NN) rowptr[idx] = sm[t] - v;
    if (t == 511) part[blockIdx.x] = sm[511];
}

__global__ __launch_bounds__(128) void k_scan2(const int* __restrict__ part,
                                               int* __restrict__ partoff,
                                               int* __restrict__ rowptr) {
    __shared__ int sm[128];
    const int t = threadIdx.x;
    const int NB = (NN + 511) / 512;
    int v = (t < NB) ? part[t] : 0;
    sm[t] = v;
    __syncthreads();
    #pragma unroll
    for (int off = 1; off < 128; off <<= 1) {
        int y = (t >= off) ? sm[t - off] : 0;
        __syncthreads();
        sm[t] += y;
        __syncthreads();
    }
    if (t < NB) partoff[t] = sm[t] - v;
    if (t == 0) rowptr[NN] = NE;
}

__global__ __launch_bounds__(512) void k_fix(int* __restrict__ rowptr,
                                             const int* __restrict__ partoff,
                                             int* __restrict__ cursor) {
    const int idx = blockIdx.x * 512 + threadIdx.x;
    if (idx < NN) {
        int r = rowptr[idx] + partoff[blockIdx.x];
        rowptr[idx] = r;
        cursor[idx] = r;
    }
}

__global__ __launch_bounds__(256) void k_bucket(
    const int* __restrict__ snd, const int* __restrict__ rcv,
    int* __restrict__ cursor, int* __restrict__ csr_snd,
    int* __restrict__ csr_pos) {
    int e = blockIdx.x * 256 + threadIdx.x;
    if (e < NE) {
        int pos = atomicAdd(&cursor[rcv[e]], 1);
        csr_snd[pos] = snd[e];
        csr_pos[e] = pos;
    }
}

// ---------- fused edge pass: sequential edges, permuted columns ------------
// chunk c, lane j -> EMB col j*8+c (lane owns 8 consecutive cols).
// Head = lane pair; reduce = one shfl_xor(1).
__global__ __launch_bounds__(256) void k_edge_attn(
    const float* __restrict__ EF, const float* __restrict__ We,
    const float* __restrict__ Web, const float* __restrict__ Av,
    const float* __restrict__ hbuf, const int* __restrict__ snd,
    const int* __restrict__ rcv, const int* __restrict__ csr_pos,
    float* __restrict__ ex_csr) {
    __shared__ bf16x8 BH[1024];
    __shared__ bf16x8 BL[1024];
    for (int t = threadIdx.x; t < 1024; t += 256) {
        int ckk = t >> 6;
        int lane = t & 63;
        int c = ckk >> 1;
        int colg = (lane & 15) * 8 + c;            // permuted column
        int kb = (ckk & 1) * 32 + (lane >> 4) * 8;
        bf16x8 vh, vl;
        #pragma unroll
        for (int j = 0; j < 8; ++j) {
            float f = We[(size_t)(kb + j) * EMB + colg];
            unsigned short hb = rne16(f);
            float fh = __uint_as_float((unsigned)hb << 16);
            vh[j] = (short)hb;
            vl[j] = (short)rne16(f - fh);
        }
        BH[t] = vh;
        BL[t] = vl;
    }
    __syncthreads();

    const int l = threadIdx.x & 63;
    const int lanecol = l & 15;
    const int q = l >> 4;
    const int wid = (blockIdx.x << 2) + (threadIdx.x >> 6);
    const int nW = gridDim.x << 2;

    float4 wbv0 = *(const float4*)&Web[lanecol * 8];
    float4 wbv1 = *(const float4*)&Web[lanecol * 8 + 4];
    float4 avv0 = *(const float4*)&Av[lanecol * 8];
    float4 avv1 = *(const float4*)&Av[lanecol * 8 + 4];
    float web[8] = {wbv0.x, wbv0.y, wbv0.z, wbv0.w, wbv1.x, wbv1.y, wbv1.z, wbv1.w};
    float av[8]  = {avv0.x, avv0.y, avv0.z, avv0.w, avv1.x, avv1.y, avv1.z, avv1.w};

    const int NT = NE / 16;
    for (int tIdx = wid; tIdx < NT; tIdx += nW) {
        const int e0 = tIdx * 16;
        // coalesced: wave reads 16 consecutive EF rows (4 KB burst)
        const float* ar = EF + (size_t)(e0 + lanecol) * ED + q * 8;
        float fa[16];
        *(float4*)&fa[0]  = *(const float4*)ar;
        *(float4*)&fa[4]  = *(const float4*)(ar + 4);
        *(float4*)&fa[8]  = *(const float4*)(ar + 32);
        *(float4*)&fa[12] = *(const float4*)(ar + 36);
        bf16x8 ahi[2], alo[2];
        #pragma unroll
        for (int kk = 0; kk < 2; ++kk) {
            #pragma unroll
            for (int j = 0; j < 8; ++j) {
                float f = fa[kk * 8 + j];
                unsigned short hb = rne16(f);
                float fh = __uint_as_float((unsigned)hb << 16);
                ahi[kk][j] = (short)hb;
                alo[kk][j] = (short)rne16(f - fh);
            }
        }
        f32x4 acc[8];
        #pragma unroll
        for (int c = 0; c < 8; ++c) acc[c] = (f32x4){0.f, 0.f, 0.f, 0.f};
        #pragma unroll
        for (int c = 0; c < 8; ++c) {
            #pragma unroll
            for (int kk = 0; kk < 2; ++kk) {
                bf16x8 bh = BH[(c * 2 + kk) * 64 + l];
                bf16x8 bl = BL[(c * 2 + kk) * 64 + l];
                acc[c] = __builtin_amdgcn_mfma_f32_16x16x32_bf16(ahi[kk], bh, acc[c], 0, 0, 0);
                acc[c] = __builtin_amdgcn_mfma_f32_16x16x32_bf16(alo[kk], bh, acc[c], 0, 0, 0);
                acc[c] = __builtin_amdgcn_mfma_f32_16x16x32_bf16(ahi[kk], bl, acc[c], 0, 0, 0);
            }
        }
        #pragma unroll
        for (int r = 0; r < 4; ++r) {
            const int e = e0 + (q << 2) + r;
            const int s = snd[e], rn = rcv[e];
            const float* hs = hbuf + (size_t)s * EMB + lanecol * 8;
            const float* hr = hbuf + (size_t)rn * EMB + lanecol * 8;
            float4 hs0 = *(const float4*)hs;
            float4 hs1 = *(const float4*)(hs + 4);
            float4 hr0 = *(const float4*)hr;
            float4 hr1 = *(const float4*)(hr + 4);
            float hsv[8] = {hs0.x, hs0.y, hs0.z, hs0.w, hs1.x, hs1.y, hs1.z, hs1.w};
            float hrv[8] = {hr0.x, hr0.y, hr0.z, hr0.w, hr1.x, hr1.y, hr1.z, hr1.w};
            float pp = 0.f;
            #pragma unroll
            for (int c = 0; c < 8; ++c) {
                float v = acc[c][r] + web[c] + hsv[c] + hrv[c];
                pp = fmaf(mishf(v), av[c], pp);
            }
            pp += __shfl_xor(pp, 1, 16);
            if ((lanecol & 1) == 0) {
                const int pos = csr_pos[e];
                ex_csr[(size_t)pos * NH + (lanecol >> 1)] = __expf(pp);
            }
        }
    }
}

// --------- segmented aggregation: one wave per node, no atomics ------------
__global__ __launch_bounds__(256) void k_agg(
    const float* __restrict__ hbuf, const int* __restrict__ csr_snd,
    const float* __restrict__ ex_csr, const int* __restrict__ rowptr,
    float* __restrict__ out) {
    const int l = threadIdx.x & 63;
    const int node = blockIdx.x * 4 + (threadIdx.x >> 6);
    if (node >= NN) return;
    const int beg = rowptr[node], end = rowptr[node + 1];
    const int h0 = l >> 4, h1 = 4 + (l >> 4);
    float acc0 = 0.f, acc1 = 0.f, den0 = 0.f, den1 = 0.f;
    int s = (beg < end) ? csr_snd[beg] : 0;
    for (int j = beg; j < end; ++j) {
        int snext = (j + 1 < end) ? csr_snd[j + 1] : 0;
        float ex0 = ex_csr[(size_t)j * NH + h0];
        float ex1 = ex_csr[(size_t)j * NH + h1];
        const float* hp = hbuf + (size_t)s * EMB;
        float hs0 = hp[l];
        float hs1 = hp[l + 64];
        acc0 = fmaf(ex0, hs0, acc0);
        acc1 = fmaf(ex1, hs1, acc1);
        den0 += ex0;
        den1 += ex1;
        s = snext;
    }
    float o0 = (end > beg) ? acc0 / den0 : 0.f;
    float o1 = (end > beg) ? acc1 / den1 : 0.f;
    out[(size_t)node * EMB + l] = o0;
    out[(size_t)node * EMB + l + 64] = o1;
}

extern "C" void kernel_launch(void* const* d_in, const int* in_sizes, int n_in,
                              void* d_out, int out_size, void* d_ws, size_t ws_size,
                              hipStream_t stream) {
    const float* X   = (const float*)d_in[0];
    const float* EF  = (const float*)d_in[1];
    const float* W   = (const float*)d_in[2];
    const float* Wb  = (const float*)d_in[3];
    const float* We  = (const float*)d_in[4];
    const float* Web = (const float*)d_in[5];
    const float* Av  = (const float*)d_in[6];
    const int* snd   = (const int*)d_in[7];
    const int* rcv   = (const int*)d_in[8];
    float* out = (float*)d_out;

    char* ws = (char*)d_ws;
    size_t off = 0;
    float* hbuf   = (float*)(ws + off); off += (size_t)NN * EMB * 4;
    float* ex_csr = (float*)(ws + off); off += (size_t)NE * NH * 4;
    int* csr_snd  = (int*)(ws + off);   off += (size_t)NE * 4;
    int* csr_pos  = (int*)(ws + off);   off += (size_t)NE * 4;
    int* rowptr   = (int*)(ws + off);   off += (size_t)(NN + 1) * 4;
    int* cursor   = (int*)(ws + off);   off += (size_t)NN * 4;
    int* part     = (int*)(ws + off);   off += 512;
    int* partoff  = (int*)(ws + off);   off += 512;
    int* cnt      = cursor;  // alias: cnt consumed before k_fix rewrites cursor

    const int NB = (NN + 511) / 512;

    hipMemsetAsync(cnt, 0, (size_t)NN * sizeof(int), stream);
    k_node_proj<<<(NN + 31) / 32, 256, 0, stream>>>(X, W, Wb, hbuf);
    k_hist<<<NE / 256, 256, 0, stream>>>(rcv, cnt);
    k_part<<<NB, 512, 0, stream>>>(cnt, rowptr, part);
    k_scan2<<<1, 128, 0, stream>>>(part, partoff, rowptr);
    k_fix<<<NB, 512, 0, stream>>>(rowptr, partoff, cursor);
    k_bucket<<<NE / 256, 256, 0, stream>>>(snd, rcv, cursor, csr_snd, csr_pos);
    k_edge_attn<<<2048, 256, 0, stream>>>(EF, We, Web, Av, hbuf, snd, rcv, csr_pos, ex_csr);
    k_agg<<<(NN + 3) / 4, 256, 0, stream>>>(hbuf, csr_snd, ex_csr, rowptr, out);
}

// Round 6
// 425.183 us; speedup vs baseline: 2.7919x; 1.1171x over previous
//
#include <hip/hip_runtime.h>
#include <math.h>

#define NN 50000
#define NE 800000
#define IND 256
#define ED 64
#define EMB 128
#define NH 8
#define HD 16

typedef short bf16x8 __attribute__((ext_vector_type(8)));
typedef float f32x4 __attribute__((ext_vector_type(4)));

#define NPROJ ((NN + 31) / 32)          // 1563 proj blocks
#define NHIST ((NE + 255) / 256)        // 3125 hist blocks

__device__ __forceinline__ unsigned short rne16(float f) {
    unsigned u = __float_as_uint(f);
    unsigned r = u + 0x7FFFu + ((u >> 16) & 1u);
    return (unsigned short)(r >> 16);
}

__device__ __forceinline__ float bf2f(short s) {
    return __uint_as_float(((unsigned)(unsigned short)s) << 16);
}

__device__ __forceinline__ float mishf(float v) {
    float t = __expf(fminf(v, 20.f));
    float u = 1.f + t;
    u = u * u;
    return v * (u - 1.f) * __builtin_amdgcn_rcpf(u + 1.f);
}

// ------- fused: node projection (blocks < NPROJ) + rcv histogram -----------
__global__ __launch_bounds__(256) void k_proj_hist(
    const float* __restrict__ X, const float* __restrict__ W,
    const float* __restrict__ b, float* __restrict__ hout,
    short* __restrict__ hbf, const int* __restrict__ rcv,
    int* __restrict__ cnt) {
    if (blockIdx.x >= NPROJ) {          // histogram part
        int e = (blockIdx.x - NPROJ) * 256 + threadIdx.x;
        if (e < NE) atomicAdd(&cnt[rcv[e]], 1);
        return;
    }
    __shared__ float As[32][32];
    __shared__ float Ws[32][128];
    const int row0 = blockIdx.x * 32;
    const int tid = threadIdx.x;
    const int col = (tid & 31) * 4;
    const int rb  = (tid >> 5) * 4;
    float acc[4][4] = {};
    for (int k0 = 0; k0 < IND; k0 += 32) {
        {
            int r = tid >> 5, kk = tid & 31;
            #pragma unroll
            for (int i = 0; i < 4; ++i) {
                int rr = r + i * 8;
                int gr = row0 + rr;
                As[rr][kk] = (gr < NN) ? X[(size_t)gr * IND + k0 + kk] : 0.f;
            }
        }
        {
            int j = tid & 127, kb = tid >> 7;
            #pragma unroll
            for (int i = 0; i < 16; ++i) {
                int kk = kb + i * 2;
                Ws[kk][j] = W[(size_t)(k0 + kk) * EMB + j];
            }
        }
        __syncthreads();
        #pragma unroll
        for (int kk = 0; kk < 32; ++kk) {
            float4 wv = *(const float4*)&Ws[kk][col];
            float av[4];
            #pragma unroll
            for (int r = 0; r < 4; ++r) av[r] = As[rb + r][kk];
            #pragma unroll
            for (int r = 0; r < 4; ++r) {
                acc[r][0] = fmaf(av[r], wv.x, acc[r][0]);
                acc[r][1] = fmaf(av[r], wv.y, acc[r][1]);
                acc[r][2] = fmaf(av[r], wv.z, acc[r][2]);
                acc[r][3] = fmaf(av[r], wv.w, acc[r][3]);
            }
        }
        __syncthreads();
    }
    #pragma unroll
    for (int r = 0; r < 4; ++r) {
        int gr = row0 + rb + r;
        if (gr < NN) {
            float4 o;
            o.x = acc[r][0] + b[col];
            o.y = acc[r][1] + b[col + 1];
            o.z = acc[r][2] + b[col + 2];
            o.w = acc[r][3] + b[col + 3];
            *(float4*)&hout[(size_t)gr * EMB + col] = o;
            short4 hb;
            hb.x = (short)rne16(o.x);
            hb.y = (short)rne16(o.y);
            hb.z = (short)rne16(o.z);
            hb.w = (short)rne16(o.w);
            *(short4*)&hbf[(size_t)gr * EMB + col] = hb;
        }
    }
}

// ---------------- CSR build ------------------------------------------------
__global__ __launch_bounds__(512) void k_part(const int* __restrict__ cnt,
                                              int* __restrict__ rowptr,
                                              int* __restrict__ part) {
    __shared__ int sm[512];
    const int t = threadIdx.x;
    const int idx = blockIdx.x * 512 + t;
    int v = (idx < NN) ? cnt[idx] : 0;
    sm[t] = v;
    __syncthreads();
    #pragma unroll
    for (int off = 1; off < 512; off <<= 1) {
        int y = (t >= off) ? sm[t - off] : 0;
        __syncthreads();
        sm[t] += y;
        __syncthreads();
    }
    if (idx < NN) rowptr[idx] = sm[t] - v;
    if (t == 511) part[blockIdx.x] = sm[511];
}

__global__ __launch_bounds__(128) void k_scan2(const int* __restrict__ part,
                                               int* __restrict__ partoff,
                                               int* __restrict__ rowptr) {
    __shared__ int sm[128];
    const int t = threadIdx.x;
    const int NB = (NN + 511) / 512;
    int v = (t < NB) ? part[t] : 0;
    sm[t] = v;
    __syncthreads();
    #pragma unroll
    for (int off = 1; off < 128; off <<= 1) {
        int y = (t >= off) ? sm[t - off] : 0;
        __syncthreads();
        sm[t] += y;
        __syncthreads();
    }
    if (t < NB) partoff[t] = sm[t] - v;
    if (t == 0) rowptr[NN] = NE;
}

__global__ __launch_bounds__(512) void k_fix(int* __restrict__ rowptr,
                                             const int* __restrict__ partoff,
                                             int* __restrict__ cursor) {
    const int idx = blockIdx.x * 512 + threadIdx.x;
    if (idx < NN) {
        int r = rowptr[idx] + partoff[blockIdx.x];
        rowptr[idx] = r;
        cursor[idx] = r;
    }
}

__global__ __launch_bounds__(256) void k_bucket(
    const int* __restrict__ snd, const int* __restrict__ rcv,
    int* __restrict__ cursor, int* __restrict__ csr_snd,
    int* __restrict__ csr_pos) {
    int e = blockIdx.x * 256 + threadIdx.x;
    if (e < NE) {
        int pos = atomicAdd(&cursor[rcv[e]], 1);
        csr_snd[pos] = snd[e];
        csr_pos[e] = pos;
    }
}

// ---------- fused edge pass: sequential edges, permuted cols, bf16 h -------
__global__ __launch_bounds__(256) void k_edge_attn(
    const float* __restrict__ EF, const float* __restrict__ We,
    const float* __restrict__ Web, const float* __restrict__ Av,
    const short* __restrict__ hbf, const int* __restrict__ snd,
    const int* __restrict__ rcv, const int* __restrict__ csr_pos,
    float* __restrict__ ex_csr) {
    __shared__ bf16x8 BH[1024];
    __shared__ bf16x8 BL[1024];
    for (int t = threadIdx.x; t < 1024; t += 256) {
        int ckk = t >> 6;
        int lane = t & 63;
        int c = ckk >> 1;
        int colg = (lane & 15) * 8 + c;            // permuted column
        int kb = (ckk & 1) * 32 + (lane >> 4) * 8;
        bf16x8 vh, vl;
        #pragma unroll
        for (int j = 0; j < 8; ++j) {
            float f = We[(size_t)(kb + j) * EMB + colg];
            unsigned short hb = rne16(f);
            float fh = __uint_as_float((unsigned)hb << 16);
            vh[j] = (short)hb;
            vl[j] = (short)rne16(f - fh);
        }
        BH[t] = vh;
        BL[t] = vl;
    }
    __syncthreads();

    const int l = threadIdx.x & 63;
    const int lanecol = l & 15;
    const int q = l >> 4;
    const int wid = (blockIdx.x << 2) + (threadIdx.x >> 6);
    const int nW = gridDim.x << 2;

    float4 wbv0 = *(const float4*)&Web[lanecol * 8];
    float4 wbv1 = *(const float4*)&Web[lanecol * 8 + 4];
    float4 avv0 = *(const float4*)&Av[lanecol * 8];
    float4 avv1 = *(const float4*)&Av[lanecol * 8 + 4];
    float web[8] = {wbv0.x, wbv0.y, wbv0.z, wbv0.w, wbv1.x, wbv1.y, wbv1.z, wbv1.w};
    float av[8]  = {avv0.x, avv0.y, avv0.z, avv0.w, avv1.x, avv1.y, avv1.z, avv1.w};

    const int NT = NE / 16;
    for (int tIdx = wid; tIdx < NT; tIdx += nW) {
        const int e0 = tIdx * 16;
        const float* ar = EF + (size_t)(e0 + lanecol) * ED + q * 8;
        float fa[16];
        *(float4*)&fa[0]  = *(const float4*)ar;
        *(float4*)&fa[4]  = *(const float4*)(ar + 4);
        *(float4*)&fa[8]  = *(const float4*)(ar + 32);
        *(float4*)&fa[12] = *(const float4*)(ar + 36);
        bf16x8 ahi[2], alo[2];
        #pragma unroll
        for (int kk = 0; kk < 2; ++kk) {
            #pragma unroll
            for (int j = 0; j < 8; ++j) {
                float f = fa[kk * 8 + j];
                unsigned short hb = rne16(f);
                float fh = __uint_as_float((unsigned)hb << 16);
                ahi[kk][j] = (short)hb;
                alo[kk][j] = (short)rne16(f - fh);
            }
        }
        f32x4 acc[8];
        #pragma unroll
        for (int c = 0; c < 8; ++c) acc[c] = (f32x4){0.f, 0.f, 0.f, 0.f};
        #pragma unroll
        for (int c = 0; c < 8; ++c) {
            #pragma unroll
            for (int kk = 0; kk < 2; ++kk) {
                bf16x8 bh = BH[(c * 2 + kk) * 64 + l];
                bf16x8 bl = BL[(c * 2 + kk) * 64 + l];
                acc[c] = __builtin_amdgcn_mfma_f32_16x16x32_bf16(ahi[kk], bh, acc[c], 0, 0, 0);
                acc[c] = __builtin_amdgcn_mfma_f32_16x16x32_bf16(alo[kk], bh, acc[c], 0, 0, 0);
                acc[c] = __builtin_amdgcn_mfma_f32_16x16x32_bf16(ahi[kk], bl, acc[c], 0, 0, 0);
            }
        }
        #pragma unroll
        for (int r = 0; r < 4; ++r) {
            const int e = e0 + (q << 2) + r;
            const int s = snd[e], rn = rcv[e];
            // bf16 h rows: one 16B load per row per lane (256B/row across group)
            bf16x8 hsv8 = *(const bf16x8*)(hbf + (size_t)s * EMB + lanecol * 8);
            bf16x8 hrv8 = *(const bf16x8*)(hbf + (size_t)rn * EMB + lanecol * 8);
            float pp = 0.f;
            #pragma unroll
            for (int c = 0; c < 8; ++c) {
                float v = acc[c][r] + web[c] + bf2f(hsv8[c]) + bf2f(hrv8[c]);
                pp = fmaf(mishf(v), av[c], pp);
            }
            pp += __shfl_xor(pp, 1, 16);
            if ((lanecol & 1) == 0) {
                const int pos = csr_pos[e];
                ex_csr[(size_t)pos * NH + (lanecol >> 1)] = __expf(pp);
            }
        }
    }
}

// --------- segmented aggregation: 4-wide chunked gathers -------------------
__global__ __launch_bounds__(256) void k_agg(
    const float* __restrict__ hbuf, const int* __restrict__ csr_snd,
    const float* __restrict__ ex_csr, const int* __restrict__ rowptr,
    float* __restrict__ out) {
    const int l = threadIdx.x & 63;
    const int node = blockIdx.x * 4 + (threadIdx.x >> 6);
    if (node >= NN) return;
    const int beg = rowptr[node], end = rowptr[node + 1];
    const int h0 = l >> 4, h1 = 4 + (l >> 4);
    float acc0 = 0.f, acc1 = 0.f, den0 = 0.f, den1 = 0.f;
    int j = beg;
    for (; j + 4 <= end; j += 4) {
        int s[4];
        float ex0[4], ex1[4], hs0[4], hs1[4];
        #pragma unroll
        for (int i = 0; i < 4; ++i) s[i] = csr_snd[j + i];
        #pragma unroll
        for (int i = 0; i < 4; ++i) {
            ex0[i] = ex_csr[(size_t)(j + i) * NH + h0];
            ex1[i] = ex_csr[(size_t)(j + i) * NH + h1];
        }
        #pragma unroll
        for (int i = 0; i < 4; ++i) {
            const float* hp = hbuf + (size_t)s[i] * EMB;
            hs0[i] = hp[l];
            hs1[i] = hp[l + 64];
        }
        #pragma unroll
        for (int i = 0; i < 4; ++i) {
            acc0 = fmaf(ex0[i], hs0[i], acc0);
            acc1 = fmaf(ex1[i], hs1[i], acc1);
            den0 += ex0[i];
            den1 += ex1[i];
        }
    }
    for (; j < end; ++j) {
        float ex0 = ex_csr[(size_t)j * NH + h0];
        float ex1 = ex_csr[(size_t)j * NH + h1];
        const float* hp = hbuf + (size_t)csr_snd[j] * EMB;
        acc0 = fmaf(ex0, hp[l], acc0);
        acc1 = fmaf(ex1, hp[l + 64], acc1);
        den0 += ex0;
        den1 += ex1;
    }
    float o0 = (end > beg) ? acc0 / den0 : 0.f;
    float o1 = (end > beg) ? acc1 / den1 : 0.f;
    out[(size_t)node * EMB + l] = o0;
    out[(size_t)node * EMB + l + 64] = o1;
}

extern "C" void kernel_launch(void* const* d_in, const int* in_sizes, int n_in,
                              void* d_out, int out_size, void* d_ws, size_t ws_size,
                              hipStream_t stream) {
    const float* X   = (const float*)d_in[0];
    const float* EF  = (const float*)d_in[1];
    const float* W   = (const float*)d_in[2];
    const float* Wb  = (const float*)d_in[3];
    const float* We  = (const float*)d_in[4];
    const float* Web = (const float*)d_in[5];
    const float* Av  = (const float*)d_in[6];
    const int* snd   = (const int*)d_in[7];
    const int* rcv   = (const int*)d_in[8];
    float* out = (float*)d_out;

    char* ws = (char*)d_ws;
    size_t off = 0;
    float* hbuf   = (float*)(ws + off); off += (size_t)NN * EMB * 4;   // 25.6 MB
    float* ex_csr = (float*)(ws + off); off += (size_t)NE * NH * 4;    // 25.6 MB
    int* csr_snd  = (int*)(ws + off);   off += (size_t)NE * 4;         // 3.2 MB
    int* csr_pos  = (int*)(ws + off);   off += (size_t)NE * 4;         // 3.2 MB
    int* rowptr   = (int*)(ws + off);   off += (size_t)(NN + 1) * 4;
    int* cursor   = (int*)(ws + off);   off += (size_t)NN * 4;
    int* part     = (int*)(ws + off);   off += 512;
    int* partoff  = (int*)(ws + off);   off += 512;
    short* hbf    = (short*)(ws + off); off += (size_t)NN * EMB * 2;   // 12.8 MB
    int* cnt      = cursor;  // alias: consumed by k_part before k_fix rewrites

    const int NB = (NN + 511) / 512;

    hipMemsetAsync(cnt, 0, (size_t)NN * sizeof(int), stream);
    k_proj_hist<<<NPROJ + NHIST, 256, 0, stream>>>(X, W, Wb, hbuf, hbf, rcv, cnt);
    k_part<<<NB, 512, 0, stream>>>(cnt, rowptr, part);
    k_scan2<<<1, 128, 0, stream>>>(part, partoff, rowptr);
    k_fix<<<NB, 512, 0, stream>>>(rowptr, partoff, cursor);
    k_bucket<<<NE / 256, 256, 0, stream>>>(snd, rcv, cursor, csr_snd, csr_pos);
    k_edge_attn<<<2048, 256, 0, stream>>>(EF, We, Web, Av, hbf, snd, rcv, csr_pos, ex_csr);
    k_agg<<<(NN + 3) / 4, 256, 0, stream>>>(hbuf, csr_snd, ex_csr, rowptr, out);
}